// Round 1
// baseline (258.708 us; speedup 1.0000x reference)
//
#include <hip/hip_runtime.h>
#include <cstdint>

#define B_   32
#define CIN  256
#define COUT 256
#define H_   56
#define W_   56
#define HP   58   // padded spatial dim (pad=1 each side)
#define NCO  8    // output channels per thread in conv kernel

// ------------------------------------------------------------------
// Pack activations: bit = (x - alpha[c]) > 0, packed along C_IN into
// 8 u32 words per (b,h,w). Layout: Ap[b][hh][ww][8], hh/ww padded by 1,
// border words = 0 (matches zero-padding; corrected in conv epilogue).
// ------------------------------------------------------------------
__global__ __launch_bounds__(256) void pack_a_kernel(
    const float* __restrict__ x, const float* __restrict__ alpha,
    uint32_t* __restrict__ Ap) {
  int ww = threadIdx.x & 63;
  int q  = threadIdx.x >> 6;
  int hh = blockIdx.x * 4 + q;
  int b  = blockIdx.y;
  if (hh >= HP || ww >= HP) return;
  uint32_t* dst = Ap + (((size_t)b * HP + hh) * HP + ww) * 8;
  if (hh == 0 || hh == HP - 1 || ww == 0 || ww == HP - 1) {
    uint4 z = make_uint4(0u, 0u, 0u, 0u);
    *(uint4*)dst = z;
    *(uint4*)(dst + 4) = z;
    return;
  }
  int h = hh - 1, w = ww - 1;
  const float* xp = x + (size_t)b * CIN * H_ * W_ + (size_t)h * W_ + w;
  uint32_t wv[8];
  #pragma unroll
  for (int k = 0; k < 8; ++k) {
    uint32_t cur = 0u;
    #pragma unroll
    for (int i = 0; i < 32; ++i) {
      int c = k * 32 + i;
      float d = xp[(size_t)c * (H_ * W_)] - alpha[c];
      cur |= (d > 0.0f) ? (1u << i) : 0u;
    }
    wv[k] = cur;
  }
  *(uint4*)dst       = *(uint4*)&wv[0];
  *(uint4*)(dst + 4) = *(uint4*)&wv[4];
}

// ------------------------------------------------------------------
// Pack weights: bit = w > 0, packed along C_IN.
// Layout: Wp[co][tap(9)][8 words]; pw[co][tap] = popcount of the 256 bits.
// ------------------------------------------------------------------
__global__ __launch_bounds__(256) void pack_w_kernel(
    const float* __restrict__ wt, uint32_t* __restrict__ Wp,
    uint32_t* __restrict__ pw) {
  int t = blockIdx.x * 256 + threadIdx.x;
  if (t >= COUT * 9) return;
  int co = t / 9;
  int tap = t - co * 9;
  const float* w0 = wt + (size_t)co * CIN * 9 + tap;   // stride 9 over ci
  int pc = 0;
  #pragma unroll
  for (int k = 0; k < 8; ++k) {
    uint32_t cur = 0u;
    #pragma unroll
    for (int i = 0; i < 32; ++i) {
      float v = w0[(size_t)(k * 32 + i) * 9];
      cur |= (v > 0.0f) ? (1u << i) : 0u;
    }
    Wp[(size_t)t * 8 + k] = cur;
    pc += __popc(cur);
  }
  pw[t] = (uint32_t)pc;
}

// ------------------------------------------------------------------
// XNOR conv: out[b][co][oh][ow] = sum over taps of (256 - 2*popc(A^W)),
// zero-pad handled via border correction with pw.
// Block: 256 threads = 64 lanes (ow, 56 active) x 4 (oh rows).
// Grid: (COUT/NCO, 56/4, B). Each thread computes NCO consecutive co.
// ------------------------------------------------------------------
__global__ __launch_bounds__(256) void conv_kernel(
    const uint32_t* __restrict__ Ap, const uint32_t* __restrict__ Wp,
    const uint32_t* __restrict__ pw, float* __restrict__ out) {
  int ow = threadIdx.x & 63;
  int q  = threadIdx.x >> 6;
  if (ow >= W_) return;
  int oh  = blockIdx.y * 4 + q;
  int co0 = blockIdx.x * NCO;
  int b   = blockIdx.z;

  // padded coords: tap (kh,kw) reads Ap[b][oh+kh][ow+kw]
  const uint32_t* ab = Ap + (((size_t)b * HP + oh) * HP + ow) * 8;

  int acc[NCO];
  #pragma unroll
  for (int c = 0; c < NCO; ++c) acc[c] = 0;

  #pragma unroll
  for (int kh = 0; kh < 3; ++kh) {
    #pragma unroll
    for (int kw = 0; kw < 3; ++kw) {
      const uint32_t* ap = ab + ((size_t)kh * HP + kw) * 8;
      uint4 av0 = *(const uint4*)ap;
      uint4 av1 = *(const uint4*)(ap + 4);
      uint32_t a[8] = {av0.x, av0.y, av0.z, av0.w, av1.x, av1.y, av1.z, av1.w};
      int tap = kh * 3 + kw;
      #pragma unroll
      for (int c = 0; c < NCO; ++c) {
        const uint32_t* wp = Wp + ((size_t)(co0 + c) * 9 + tap) * 8;  // wave-uniform -> s_load
        int s = 0;
        #pragma unroll
        for (int j = 0; j < 8; ++j) s += __popc(a[j] ^ wp[j]);
        acc[c] += s;
      }
    }
  }

  // border correction: invalid taps contributed (256 - 2*pw) via zero words
  int corr[NCO];
  #pragma unroll
  for (int c = 0; c < NCO; ++c) corr[c] = 0;
  bool top = (oh == 0), bot = (oh == H_ - 1), left = (ow == 0), right = (ow == W_ - 1);
  if (top || bot || left || right) {
    #pragma unroll
    for (int kh = 0; kh < 3; ++kh) {
      #pragma unroll
      for (int kw = 0; kw < 3; ++kw) {
        bool inv = (top && kh == 0) || (bot && kh == 2) ||
                   (left && kw == 0) || (right && kw == 2);
        if (inv) {
          #pragma unroll
          for (int c = 0; c < NCO; ++c)
            corr[c] += 256 - 2 * (int)pw[(size_t)(co0 + c) * 9 + kh * 3 + kw];
        }
      }
    }
  }

  size_t ob = (((size_t)b * COUT + co0) * H_ + oh) * W_ + ow;
  #pragma unroll
  for (int c = 0; c < NCO; ++c) {
    out[ob + (size_t)c * (H_ * W_)] = (float)(9 * 256 - 2 * acc[c] - corr[c]);
  }
}

extern "C" void kernel_launch(void* const* d_in, const int* in_sizes, int n_in,
                              void* d_out, int out_size, void* d_ws, size_t ws_size,
                              hipStream_t stream) {
  const float* x     = (const float*)d_in[0];
  const float* alpha = (const float*)d_in[1];
  const float* wt    = (const float*)d_in[2];
  float* out = (float*)d_out;

  uint32_t* Ap = (uint32_t*)d_ws;                       // 32*58*58*8 u32 = 3,444,736 B
  uint32_t* Wp = Ap + (size_t)B_ * HP * HP * 8;         // 256*9*8 u32 = 73,728 B
  uint32_t* pw = Wp + (size_t)COUT * 9 * 8;             // 256*9 u32 = 9,216 B

  dim3 gA((HP + 3) / 4, B_);        // 15 x 32
  pack_a_kernel<<<gA, 256, 0, stream>>>(x, alpha, Ap);

  pack_w_kernel<<<9, 256, 0, stream>>>(wt, Wp, pw);

  dim3 gC(COUT / NCO, H_ / 4, B_);  // 32 x 14 x 32
  conv_kernel<<<gC, 256, 0, stream>>>(Ap, Wp, pw, out);
}

// Round 2
// 156.517 us; speedup vs baseline: 1.6529x; 1.6529x over previous
//
#include <hip/hip_runtime.h>
#include <cstdint>

#define B_   32
#define CIN  256
#define COUT 256
#define H_   56
#define W_   56
#define HP   58   // padded spatial dim (pad=1 each side)
#define NCO  8    // output channels per thread
#define OHT  2    // output rows per thread

// ------------------------------------------------------------------
// Pack activations: bit = (x - alpha[c]) > 0, packed along C_IN into
// 8 u32 words per (b,h,w). Layout: Ap[b][hh][ww][8], hh/ww padded by 1,
// border words = 0 (matches zero-padding; corrected in conv epilogue).
// ------------------------------------------------------------------
__global__ __launch_bounds__(256) void pack_a_kernel(
    const float* __restrict__ x, const float* __restrict__ alpha,
    uint32_t* __restrict__ Ap) {
  int ww = threadIdx.x & 63;
  int q  = threadIdx.x >> 6;
  int hh = blockIdx.x * 4 + q;
  int b  = blockIdx.y;
  if (hh >= HP || ww >= HP) return;
  uint32_t* dst = Ap + (((b * HP + hh) * HP + ww) * 8);
  if (hh == 0 || hh == HP - 1 || ww == 0 || ww == HP - 1) {
    uint4 z = make_uint4(0u, 0u, 0u, 0u);
    *(uint4*)dst = z;
    *(uint4*)(dst + 4) = z;
    return;
  }
  int h = hh - 1, w = ww - 1;
  const float* xp = x + (size_t)b * CIN * H_ * W_ + h * W_ + w;
  uint32_t wv[8];
  #pragma unroll
  for (int k = 0; k < 8; ++k) {
    uint32_t cur = 0u;
    #pragma unroll
    for (int i = 0; i < 32; ++i) {
      int c = k * 32 + i;
      float d = xp[c * (H_ * W_)] - alpha[c];
      cur |= (d > 0.0f) ? (1u << i) : 0u;
    }
    wv[k] = cur;
  }
  *(uint4*)dst       = *(uint4*)&wv[0];
  *(uint4*)(dst + 4) = *(uint4*)&wv[4];
}

// ------------------------------------------------------------------
// Pack weights: bit = w > 0, packed along C_IN.
// NEW layout: Wp[tap][co][8 words]  (co-major within tap -> one tap's
// 8-channel batch for a block is 256 contiguous bytes = 4x s_load_dwordx16)
// pw[tap][co] = popcount of the 256 bits (for border correction).
// ------------------------------------------------------------------
__global__ __launch_bounds__(256) void pack_w_kernel(
    const float* __restrict__ wt, uint32_t* __restrict__ Wp,
    uint32_t* __restrict__ pw) {
  int t = blockIdx.x * 256 + threadIdx.x;
  if (t >= COUT * 9) return;
  int co = t / 9;
  int tap = t - co * 9;
  const float* w0 = wt + (size_t)co * CIN * 9 + tap;   // stride 9 over ci
  int pc = 0;
  #pragma unroll
  for (int k = 0; k < 8; ++k) {
    uint32_t cur = 0u;
    #pragma unroll
    for (int i = 0; i < 32; ++i) {
      float v = w0[(k * 32 + i) * 9];
      cur |= (v > 0.0f) ? (1u << i) : 0u;
    }
    Wp[((tap * COUT + co) * 8) + k] = cur;
    pc += __popc(cur);
  }
  pw[tap * COUT + co] = (uint32_t)pc;
}

// ------------------------------------------------------------------
// XNOR conv. Each thread: 1 ow column x OHT=2 output rows x NCO=8 co.
// Block: 256 threads = 64 lanes (ow) x 4 row-pairs. Grid: (32, 7, 32).
// W batch per tap: 64 contiguous dwords (uniform -> SGPRs via s_load).
// Core: v_xor (SGPR operand) + inline-asm fused v_bcnt accumulate.
// ------------------------------------------------------------------
__global__ __launch_bounds__(256, 8) void conv_kernel(
    const uint32_t* __restrict__ Ap, const uint32_t* __restrict__ Wp,
    const uint32_t* __restrict__ pw, float* __restrict__ out) {
  const int ow = threadIdx.x & 63;
  const int q  = threadIdx.x >> 6;
  if (ow >= W_) return;
  const int r0  = blockIdx.y * (4 * OHT) + q * OHT;   // output rows r0, r0+1
  const int co0 = blockIdx.x * NCO;
  const int b   = blockIdx.z;

  int acc0[NCO], acc1[NCO];
  #pragma unroll
  for (int c = 0; c < NCO; ++c) { acc0[c] = 0; acc1[c] = 0; }

  // padded coords: out row r taps read Ap[b][r+kh][ow+kw]
  const uint32_t* abase = Ap + (((b * HP + r0) * HP + ow) * 8);

  #pragma unroll
  for (int kh = 0; kh < 3; ++kh) {
    const uint32_t* a0p = abase + kh * (HP * 8);       // row r0+kh
    const uint32_t* a1p = a0p + (HP * 8);              // row r0+1+kh
    #pragma unroll
    for (int kw = 0; kw < 3; ++kw) {
      uint32_t a0[8], a1[8];
      *(uint4*)&a0[0] = *(const uint4*)(a0p + kw * 8);
      *(uint4*)&a0[4] = *(const uint4*)(a0p + kw * 8 + 4);
      *(uint4*)&a1[0] = *(const uint4*)(a1p + kw * 8);
      *(uint4*)&a1[4] = *(const uint4*)(a1p + kw * 8 + 4);
      const int tap = kh * 3 + kw;
      const uint32_t* wb = Wp + ((tap * COUT + co0) * 8);  // 64 contiguous dwords, uniform
      #pragma unroll
      for (int c = 0; c < NCO; ++c) {
        #pragma unroll
        for (int j = 0; j < 8; ++j) {
          uint32_t w  = wb[c * 8 + j];
          uint32_t t0 = a0[j] ^ w;
          uint32_t t1 = a1[j] ^ w;
          asm("v_bcnt_u32_b32 %0, %1, %0" : "+v"(acc0[c]) : "v"(t0));
          asm("v_bcnt_u32_b32 %0, %1, %0" : "+v"(acc1[c]) : "v"(t1));
        }
      }
    }
  }

  // border correction: invalid taps contributed (256 - 2*pw[tap][co])
  int corr0[NCO], corr1[NCO];
  #pragma unroll
  for (int c = 0; c < NCO; ++c) { corr0[c] = 0; corr1[c] = 0; }
  const bool left = (ow == 0), right = (ow == W_ - 1);
  {
    const int r = r0;
    const bool top = (r == 0), bot = (r == H_ - 1);
    if (top || bot || left || right) {
      #pragma unroll
      for (int kh = 0; kh < 3; ++kh) {
        #pragma unroll
        for (int kw = 0; kw < 3; ++kw) {
          bool inv = (top && kh == 0) || (bot && kh == 2) ||
                     (left && kw == 0) || (right && kw == 2);
          if (inv) {
            #pragma unroll
            for (int c = 0; c < NCO; ++c)
              corr0[c] += 256 - 2 * (int)pw[(kh * 3 + kw) * COUT + co0 + c];
          }
        }
      }
    }
  }
  {
    const int r = r0 + 1;
    const bool top = (r == 0), bot = (r == H_ - 1);
    if (top || bot || left || right) {
      #pragma unroll
      for (int kh = 0; kh < 3; ++kh) {
        #pragma unroll
        for (int kw = 0; kw < 3; ++kw) {
          bool inv = (top && kh == 0) || (bot && kh == 2) ||
                     (left && kw == 0) || (right && kw == 2);
          if (inv) {
            #pragma unroll
            for (int c = 0; c < NCO; ++c)
              corr1[c] += 256 - 2 * (int)pw[(kh * 3 + kw) * COUT + co0 + c];
          }
        }
      }
    }
  }

  const int ob = ((b * COUT + co0) * H_ + r0) * W_ + ow;
  #pragma unroll
  for (int c = 0; c < NCO; ++c) {
    out[ob + c * (H_ * W_)]      = (float)(9 * 256 - 2 * acc0[c] - corr0[c]);
    out[ob + c * (H_ * W_) + W_] = (float)(9 * 256 - 2 * acc1[c] - corr1[c]);
  }
}

extern "C" void kernel_launch(void* const* d_in, const int* in_sizes, int n_in,
                              void* d_out, int out_size, void* d_ws, size_t ws_size,
                              hipStream_t stream) {
  const float* x     = (const float*)d_in[0];
  const float* alpha = (const float*)d_in[1];
  const float* wt    = (const float*)d_in[2];
  float* out = (float*)d_out;

  uint32_t* Ap = (uint32_t*)d_ws;                       // 32*58*58*8 u32 = 3,444,736 B
  uint32_t* Wp = Ap + (size_t)B_ * HP * HP * 8;         // 9*256*8 u32 = 73,728 B
  uint32_t* pw = Wp + (size_t)9 * COUT * 8;             // 9*256 u32 = 9,216 B

  dim3 gA((HP + 3) / 4, B_);        // 15 x 32
  pack_a_kernel<<<gA, 256, 0, stream>>>(x, alpha, Ap);

  pack_w_kernel<<<9, 256, 0, stream>>>(wt, Wp, pw);

  dim3 gC(COUT / NCO, H_ / (4 * OHT), B_);  // 32 x 7 x 32
  conv_kernel<<<gC, 256, 0, stream>>>(Ap, Wp, pw, out);
}

// Round 3
// 155.857 us; speedup vs baseline: 1.6599x; 1.0042x over previous
//
#include <hip/hip_runtime.h>
#include <cstdint>

#define B_   32
#define CIN  256
#define COUT 256
#define H_   56
#define W_   56
#define HP   58   // padded spatial dim (pad=1 each side)
#define HP8  (HP * 8)
#define NCO  8    // output channels per thread
#define OHT  2    // output rows per thread

// ------------------------------------------------------------------
// Pack activations: bit = (x - alpha[c]) > 0, packed along C_IN into
// 8 u32 words per (b,h,w). Layout: Ap[b][hh][ww][8], hh/ww padded by 1,
// border words = 0 (matches zero-padding; corrected in conv epilogue).
// ------------------------------------------------------------------
__global__ __launch_bounds__(256) void pack_a_kernel(
    const float* __restrict__ x, const float* __restrict__ alpha,
    uint32_t* __restrict__ Ap) {
  int ww = threadIdx.x & 63;
  int q  = threadIdx.x >> 6;
  int hh = blockIdx.x * 4 + q;
  int b  = blockIdx.y;
  if (hh >= HP || ww >= HP) return;
  uint32_t* dst = Ap + (((b * HP + hh) * HP + ww) * 8);
  if (hh == 0 || hh == HP - 1 || ww == 0 || ww == HP - 1) {
    uint4 z = make_uint4(0u, 0u, 0u, 0u);
    *(uint4*)dst = z;
    *(uint4*)(dst + 4) = z;
    return;
  }
  int h = hh - 1, w = ww - 1;
  const float* xp = x + (size_t)b * CIN * H_ * W_ + h * W_ + w;
  uint32_t wv[8];
  #pragma unroll
  for (int k = 0; k < 8; ++k) {
    uint32_t cur = 0u;
    #pragma unroll
    for (int i = 0; i < 32; ++i) {
      int c = k * 32 + i;
      float d = xp[c * (H_ * W_)] - alpha[c];
      cur |= (d > 0.0f) ? (1u << i) : 0u;
    }
    wv[k] = cur;
  }
  *(uint4*)dst       = *(uint4*)&wv[0];
  *(uint4*)(dst + 4) = *(uint4*)&wv[4];
}

// ------------------------------------------------------------------
// Pack weights: bit = w > 0, packed along C_IN.
// Layout: Wp[tap][co][8 words]; pw[tap][co] = popcount (border corr).
// ------------------------------------------------------------------
__global__ __launch_bounds__(256) void pack_w_kernel(
    const float* __restrict__ wt, uint32_t* __restrict__ Wp,
    uint32_t* __restrict__ pw) {
  int t = blockIdx.x * 256 + threadIdx.x;
  if (t >= COUT * 9) return;
  int co = t / 9;
  int tap = t - co * 9;
  const float* w0 = wt + (size_t)co * CIN * 9 + tap;   // stride 9 over ci
  int pc = 0;
  #pragma unroll
  for (int k = 0; k < 8; ++k) {
    uint32_t cur = 0u;
    #pragma unroll
    for (int i = 0; i < 32; ++i) {
      float v = w0[(k * 32 + i) * 9];
      cur |= (v > 0.0f) ? (1u << i) : 0u;
    }
    Wp[((tap * COUT + co) * 8) + k] = cur;
    pc += __popc(cur);
  }
  pw[tap * COUT + co] = (uint32_t)pc;
}

// ------------------------------------------------------------------
// XNOR conv. Each thread: 1 ow column x OHT=2 output rows x NCO=8 co.
// Block: 256 threads = 64 lanes (ow) x 4 row-pairs. Grid: (32, 7, 32).
// Input rows r0..r0+3 each loaded ONCE (24 contiguous dwords) into
// rotating register buffers rA/rB/rC; taps consume row pairs per kh.
// W batches are wave-uniform -> s_load (scalar pipe).
// launch_bounds(256,4): 128-VGPR budget so rows+accs+addr all fit.
// ------------------------------------------------------------------
__global__ __launch_bounds__(256, 4) void conv_kernel(
    const uint32_t* __restrict__ Ap, const uint32_t* __restrict__ Wp,
    const uint32_t* __restrict__ pw, float* __restrict__ out) {
  const int ow = threadIdx.x & 63;
  const int q  = threadIdx.x >> 6;
  if (ow >= W_) return;
  const int r0  = blockIdx.y * (4 * OHT) + q * OHT;   // output rows r0, r0+1
  const int co0 = blockIdx.x * NCO;
  const int b   = blockIdx.z;

  // one base address; every A load is base + compile-time immediate
  const uint32_t* ap = Ap + (((b * HP + r0) * HP + ow) * 8);

  uint32_t rA[24], rB[24], rC[24];
#define LOAD_ROW(dst, off) do {                                   \
    *(uint4*)&(dst)[0]  = *(const uint4*)(ap + (off));            \
    *(uint4*)&(dst)[4]  = *(const uint4*)(ap + (off) + 4);        \
    *(uint4*)&(dst)[8]  = *(const uint4*)(ap + (off) + 8);        \
    *(uint4*)&(dst)[12] = *(const uint4*)(ap + (off) + 12);       \
    *(uint4*)&(dst)[16] = *(const uint4*)(ap + (off) + 16);       \
    *(uint4*)&(dst)[20] = *(const uint4*)(ap + (off) + 20);       \
  } while (0)

  LOAD_ROW(rA, 0);
  LOAD_ROW(rB, HP8);
  LOAD_ROW(rC, 2 * HP8);

  int acc0[NCO], acc1[NCO];
  #pragma unroll
  for (int c = 0; c < NCO; ++c) { acc0[c] = 0; acc1[c] = 0; }

  // x0 feeds output row r0 (kh = tb/3), x1 feeds output row r0+1
#define PROC(x0, x1, tb) do {                                     \
    _Pragma("unroll")                                             \
    for (int kw = 0; kw < 3; ++kw) {                              \
      const uint32_t* wb = Wp + (((tb) + kw) * COUT + co0) * 8;   \
      _Pragma("unroll")                                           \
      for (int c = 0; c < NCO; ++c) {                             \
        _Pragma("unroll")                                         \
        for (int j = 0; j < 8; ++j) {                             \
          uint32_t w  = wb[c * 8 + j];                            \
          uint32_t t0 = (x0)[kw * 8 + j] ^ w;                     \
          uint32_t t1 = (x1)[kw * 8 + j] ^ w;                     \
          asm("v_bcnt_u32_b32 %0, %1, %0" : "+v"(acc0[c]) : "v"(t0)); \
          asm("v_bcnt_u32_b32 %0, %1, %0" : "+v"(acc1[c]) : "v"(t1)); \
        }                                                         \
      }                                                           \
    }                                                             \
  } while (0)

  PROC(rA, rB, 0);          // kh=0: rows r0, r0+1
  LOAD_ROW(rA, 3 * HP8);    // row r0+3 replaces r0
  PROC(rB, rC, 3);          // kh=1: rows r0+1, r0+2
  PROC(rC, rA, 6);          // kh=2: rows r0+2, r0+3
#undef PROC
#undef LOAD_ROW

  // border correction: invalid taps contributed (256 - 2*pw[tap][co])
  int corr0[NCO], corr1[NCO];
  #pragma unroll
  for (int c = 0; c < NCO; ++c) { corr0[c] = 0; corr1[c] = 0; }
  const bool left = (ow == 0), right = (ow == W_ - 1);
  {
    const bool top = (r0 == 0), bot = (r0 == H_ - 1);
    if (top || bot || left || right) {
      #pragma unroll
      for (int kh = 0; kh < 3; ++kh) {
        #pragma unroll
        for (int kw = 0; kw < 3; ++kw) {
          bool inv = (top && kh == 0) || (bot && kh == 2) ||
                     (left && kw == 0) || (right && kw == 2);
          if (inv) {
            #pragma unroll
            for (int c = 0; c < NCO; ++c)
              corr0[c] += 256 - 2 * (int)pw[(kh * 3 + kw) * COUT + co0 + c];
          }
        }
      }
    }
  }
  {
    const int r = r0 + 1;
    const bool top = (r == 0), bot = (r == H_ - 1);
    if (top || bot || left || right) {
      #pragma unroll
      for (int kh = 0; kh < 3; ++kh) {
        #pragma unroll
        for (int kw = 0; kw < 3; ++kw) {
          bool inv = (top && kh == 0) || (bot && kh == 2) ||
                     (left && kw == 0) || (right && kw == 2);
          if (inv) {
            #pragma unroll
            for (int c = 0; c < NCO; ++c)
              corr1[c] += 256 - 2 * (int)pw[(kh * 3 + kw) * COUT + co0 + c];
          }
        }
      }
    }
  }

  const int ob = ((b * COUT + co0) * H_ + r0) * W_ + ow;
  #pragma unroll
  for (int c = 0; c < NCO; ++c) {
    out[ob + c * (H_ * W_)]      = (float)(9 * 256 - 2 * acc0[c] - corr0[c]);
    out[ob + c * (H_ * W_) + W_] = (float)(9 * 256 - 2 * acc1[c] - corr1[c]);
  }
}

extern "C" void kernel_launch(void* const* d_in, const int* in_sizes, int n_in,
                              void* d_out, int out_size, void* d_ws, size_t ws_size,
                              hipStream_t stream) {
  const float* x     = (const float*)d_in[0];
  const float* alpha = (const float*)d_in[1];
  const float* wt    = (const float*)d_in[2];
  float* out = (float*)d_out;

  uint32_t* Ap = (uint32_t*)d_ws;                       // 32*58*58*8 u32 = 3,444,736 B
  uint32_t* Wp = Ap + (size_t)B_ * HP * HP * 8;         // 9*256*8 u32 = 73,728 B
  uint32_t* pw = Wp + (size_t)9 * COUT * 8;             // 9*256 u32 = 9,216 B

  dim3 gA((HP + 3) / 4, B_);        // 15 x 32
  pack_a_kernel<<<gA, 256, 0, stream>>>(x, alpha, Ap);

  pack_w_kernel<<<9, 256, 0, stream>>>(wt, Wp, pw);

  dim3 gC(COUT / NCO, H_ / (4 * OHT), B_);  // 32 x 7 x 32
  conv_kernel<<<gC, 256, 0, stream>>>(Ap, Wp, pw, out);
}